// Round 2
// baseline (696.486 us; speedup 1.0000x reference)
//
#include <hip/hip_runtime.h>

#define N_NODES 100000
#define N_EDGES 3200000
#define IN_DIM  128
#define HID     16
#define OUTC    2

// ---------------- degree / norm ----------------

__global__ __launch_bounds__(256) void k_init_deg(float* __restrict__ deg) {
    int n = blockIdx.x * 256 + threadIdx.x;
    if (n < N_NODES) deg[n] = 1.0f;   // self-loop
}

__global__ __launch_bounds__(256) void k_count(const int* __restrict__ dst,
                                               float* __restrict__ deg) {
    int e = blockIdx.x * 256 + threadIdx.x;
    if (e < N_EDGES) atomicAdd(&deg[dst[e]], 1.0f);
}

__global__ __launch_bounds__(256) void k_dinv(float* __restrict__ deg) {
    int n = blockIdx.x * 256 + threadIdx.x;
    if (n < N_NODES) deg[n] = rsqrtf(deg[n]);   // deg >= 1 always
}

// ---------------- layer 1: g1 = (x @ W1) * dinv ----------------
// 16 threads per node; W1 (128x16 = 8KB) staged in LDS.

__global__ __launch_bounds__(256) void k_gemm1(const float* __restrict__ x,
                                               const float* __restrict__ W1,
                                               const float* __restrict__ dinv,
                                               float* __restrict__ g1) {
    __shared__ float sW[IN_DIM * HID];
    for (int i = threadIdx.x; i < IN_DIM * HID; i += 256) sW[i] = W1[i];
    __syncthreads();

    int gid = blockIdx.x * 256 + threadIdx.x;
    int n = gid >> 4;
    int k = gid & 15;
    if (n >= N_NODES) return;

    const float* xr = x + (size_t)n * IN_DIM;
    float acc = 0.f;
#pragma unroll 8
    for (int j = 0; j < IN_DIM; ++j)
        acc = fmaf(xr[j], sW[j * HID + k], acc);

    g1[n * HID + k] = acc * dinv[n];
}

// ---------------- scatter layer 1: acc1[dst] += g1[src] ----------------
// 16 lanes per edge, one channel each. Coalesced 64B gather + 64B atomic.

__global__ __launch_bounds__(256) void k_scatter1(const int* __restrict__ src,
                                                  const int* __restrict__ dst,
                                                  const float* __restrict__ g1,
                                                  float* __restrict__ acc1) {
    int tid = blockIdx.x * 256 + threadIdx.x;
    int e = tid >> 4;
    int k = tid & 15;
    if (e >= N_EDGES) return;
    int s = src[e];
    int d = dst[e];
    atomicAdd(&acc1[d * HID + k], g1[s * HID + k]);
}

// ---------------- finish layer 1 + tiny GEMM 2 ----------------
// h1 = relu(dinv*(acc1 + g1) + b1); g2 = (h1 @ W2) * dinv

__global__ __launch_bounds__(256) void k_layer1_finish(const float* __restrict__ acc1,
                                                       const float* __restrict__ g1,
                                                       const float* __restrict__ dinv,
                                                       const float* __restrict__ b1,
                                                       const float* __restrict__ W2,
                                                       float* __restrict__ g2) {
    int n = blockIdx.x * 256 + threadIdx.x;
    if (n >= N_NODES) return;
    float di = dinv[n];

    float h[HID];
    const float4* a4 = (const float4*)(acc1 + (size_t)n * HID);
    const float4* s4 = (const float4*)(g1 + (size_t)n * HID);
#pragma unroll
    for (int q = 0; q < HID / 4; ++q) {
        float4 a = a4[q];
        float4 s = s4[q];
        float v0 = di * (a.x + s.x) + b1[q * 4 + 0];
        float v1 = di * (a.y + s.y) + b1[q * 4 + 1];
        float v2 = di * (a.z + s.z) + b1[q * 4 + 2];
        float v3 = di * (a.w + s.w) + b1[q * 4 + 3];
        h[q * 4 + 0] = fmaxf(v0, 0.f);
        h[q * 4 + 1] = fmaxf(v1, 0.f);
        h[q * 4 + 2] = fmaxf(v2, 0.f);
        h[q * 4 + 3] = fmaxf(v3, 0.f);
    }

    float o0 = 0.f, o1 = 0.f;
#pragma unroll
    for (int k = 0; k < HID; ++k) {
        o0 = fmaf(h[k], W2[k * OUTC + 0], o0);
        o1 = fmaf(h[k], W2[k * OUTC + 1], o1);
    }
    g2[n * OUTC + 0] = o0 * di;
    g2[n * OUTC + 1] = o1 * di;
}

// ---------------- scatter layer 2: acc2[dst] += g2[src] ----------------

__global__ __launch_bounds__(256) void k_scatter2(const int* __restrict__ src,
                                                  const int* __restrict__ dst,
                                                  const float* __restrict__ g2,
                                                  float* __restrict__ acc2) {
    int e = blockIdx.x * 256 + threadIdx.x;
    if (e >= N_EDGES) return;
    int s = src[e];
    int d = dst[e];
    float2 v = *(const float2*)(g2 + (size_t)s * OUTC);
    atomicAdd(&acc2[d * OUTC + 0], v.x);
    atomicAdd(&acc2[d * OUTC + 1], v.y);
}

// ---------------- final: +self-loop, *dinv, +b2, log_softmax ----------------

__global__ __launch_bounds__(256) void k_final(const float* __restrict__ acc2,
                                               const float* __restrict__ g2,
                                               const float* __restrict__ dinv,
                                               const float* __restrict__ b2,
                                               float* __restrict__ out) {
    int n = blockIdx.x * 256 + threadIdx.x;
    if (n >= N_NODES) return;
    float di = dinv[n];
    float v0 = di * (acc2[n * OUTC + 0] + g2[n * OUTC + 0]) + b2[0];
    float v1 = di * (acc2[n * OUTC + 1] + g2[n * OUTC + 1]) + b2[1];
    float m = fmaxf(v0, v1);
    float lse = m + logf(expf(v0 - m) + expf(v1 - m));
    out[n * OUTC + 0] = v0 - lse;
    out[n * OUTC + 1] = v1 - lse;
}

extern "C" void kernel_launch(void* const* d_in, const int* in_sizes, int n_in,
                              void* d_out, int out_size, void* d_ws, size_t ws_size,
                              hipStream_t stream) {
    const float* x  = (const float*)d_in[0];
    const int*   ei = (const int*)d_in[1];
    const float* W1 = (const float*)d_in[2];
    const float* b1 = (const float*)d_in[3];
    const float* W2 = (const float*)d_in[4];
    const float* b2 = (const float*)d_in[5];
    float* out = (float*)d_out;

    const int* src = ei;             // edge_index[0]
    const int* dst = ei + N_EDGES;   // edge_index[1]

    float* ws   = (float*)d_ws;
    float* deg  = ws;                         // N floats (becomes dinv)
    float* g1   = deg  + N_NODES;             // 16N
    float* acc1 = g1   + 16 * N_NODES;        // 16N
    float* g2   = acc1 + 16 * N_NODES;        // 2N
    float* acc2 = g2   + 2 * N_NODES;         // 2N  (total 37N floats ~ 14.8 MB)

    hipMemsetAsync(acc1, 0, (size_t)16 * N_NODES * sizeof(float), stream);
    hipMemsetAsync(acc2, 0, (size_t)2 * N_NODES * sizeof(float), stream);

    k_init_deg<<<(N_NODES + 255) / 256, 256, 0, stream>>>(deg);
    k_count<<<(N_EDGES + 255) / 256, 256, 0, stream>>>(dst, deg);
    k_dinv<<<(N_NODES + 255) / 256, 256, 0, stream>>>(deg);
    k_gemm1<<<(N_NODES * 16 + 255) / 256, 256, 0, stream>>>(x, W1, deg, g1);
    k_scatter1<<<(N_EDGES * 16 + 255) / 256, 256, 0, stream>>>(src, dst, g1, acc1);
    k_layer1_finish<<<(N_NODES + 255) / 256, 256, 0, stream>>>(acc1, g1, deg, b1, W2, g2);
    k_scatter2<<<(N_EDGES + 255) / 256, 256, 0, stream>>>(src, dst, g2, acc2);
    k_final<<<(N_NODES + 255) / 256, 256, 0, stream>>>(acc2, g2, deg, b2, out);
}

// Round 3
// 307.658 us; speedup vs baseline: 2.2638x; 2.2638x over previous
//
#include <hip/hip_runtime.h>

#define N_NODES 100000
#define N_EDGES 3200000
#define IN_DIM  128
#define HID     16
#define OUTC    2

// scan geometry
#define SCAN_ELEMS 2048                 // per block (256 thr x 8)
#define SCAN_NB    49                   // ceil(100000/2048)

// ---------------- pass 1: count + per-edge rank ----------------
__global__ __launch_bounds__(256) void k_count_rank(const int* __restrict__ dst,
                                                    int* __restrict__ cnt,
                                                    int* __restrict__ rank) {
    int e = blockIdx.x * 256 + threadIdx.x;
    if (e < N_EDGES) rank[e] = atomicAdd(&cnt[dst[e]], 1);
}

// ---------------- scan (a): per-block sums ----------------
__global__ __launch_bounds__(256) void k_blocksum(const int* __restrict__ cnt,
                                                  int* __restrict__ bsum) {
    __shared__ int s[256];
    int base = blockIdx.x * SCAN_ELEMS + threadIdx.x * 8;
    int t = 0;
#pragma unroll
    for (int i = 0; i < 8; ++i) {
        int idx = base + i;
        t += (idx < N_NODES) ? cnt[idx] : 0;
    }
    s[threadIdx.x] = t;
    __syncthreads();
    for (int ofs = 128; ofs > 0; ofs >>= 1) {
        if (threadIdx.x < ofs) s[threadIdx.x] += s[threadIdx.x + ofs];
        __syncthreads();
    }
    if (threadIdx.x == 0) bsum[blockIdx.x] = s[0];
}

// ---------------- scan (b): exclusive scan of block sums ----------------
__global__ __launch_bounds__(64) void k_scanb(const int* __restrict__ bsum,
                                              int* __restrict__ boff) {
    if (threadIdx.x == 0) {
        int run = 0;
        for (int b = 0; b < SCAN_NB; ++b) { boff[b] = run; run += bsum[b]; }
    }
}

// ---------------- scan (c): final offsets + dinv ----------------
__global__ __launch_bounds__(256) void k_offsets(const int* __restrict__ cnt,
                                                 const int* __restrict__ boff,
                                                 int* __restrict__ off,
                                                 float* __restrict__ dinv) {
    __shared__ int s[256];
    int base = blockIdx.x * SCAN_ELEMS + threadIdx.x * 8;
    int c[8];
    int tsum = 0;
#pragma unroll
    for (int i = 0; i < 8; ++i) {
        int idx = base + i;
        c[i] = (idx < N_NODES) ? cnt[idx] : 0;
        tsum += c[i];
    }
    s[threadIdx.x] = tsum;
    __syncthreads();
    // Hillis-Steele inclusive scan over thread sums
    for (int ofs = 1; ofs < 256; ofs <<= 1) {
        int v = (threadIdx.x >= ofs) ? s[threadIdx.x - ofs] : 0;
        __syncthreads();
        s[threadIdx.x] += v;
        __syncthreads();
    }
    int tbase = boff[blockIdx.x] + s[threadIdx.x] - tsum;  // exclusive prefix
    int run = 0;
#pragma unroll
    for (int i = 0; i < 8; ++i) {
        int idx = base + i;
        if (idx < N_NODES) {
            off[idx] = tbase + run;
            dinv[idx] = rsqrtf(1.0f + (float)c[i]);   // + self-loop
        }
        run += c[i];
    }
}

// ---------------- fill CSR (atomic-free) ----------------
__global__ __launch_bounds__(256) void k_fill(const int* __restrict__ src,
                                              const int* __restrict__ dst,
                                              const int* __restrict__ rank,
                                              const int* __restrict__ off,
                                              int* __restrict__ csr) {
    int e = blockIdx.x * 256 + threadIdx.x;
    if (e >= N_EDGES) return;
    csr[off[dst[e]] + rank[e]] = src[e];
}

// ---------------- p1 = dinv * (x @ W1) ----------------
__global__ __launch_bounds__(256) void k_gemm1(const float* __restrict__ x,
                                               const float* __restrict__ W1,
                                               const float* __restrict__ dinv,
                                               float* __restrict__ p1) {
    __shared__ float sW[IN_DIM * HID];
    for (int i = threadIdx.x; i < IN_DIM * HID; i += 256) sW[i] = W1[i];
    __syncthreads();

    int gid = blockIdx.x * 256 + threadIdx.x;
    int n = gid >> 4;
    int k = gid & 15;
    if (n >= N_NODES) return;

    const float* xr = x + (size_t)n * IN_DIM;
    float acc = 0.f;
#pragma unroll 8
    for (int j = 0; j < IN_DIM; ++j)
        acc = fmaf(xr[j], sW[j * HID + k], acc);

    p1[n * HID + k] = acc * dinv[n];
}

// ---------------- gather layer 1 (+relu/bias/scale fused) ----------------
// p2[n] = dinv[n] * relu(dinv[n]*(sum_{s in N(n)} p1[s] + p1[n]) + b1)
__global__ __launch_bounds__(256) void k_gather1(const int* __restrict__ csr,
                                                 const int* __restrict__ off,
                                                 const int* __restrict__ cnt,
                                                 const float* __restrict__ p1,
                                                 const float* __restrict__ dinv,
                                                 const float* __restrict__ b1,
                                                 float* __restrict__ p2) {
    int gid = blockIdx.x * 256 + threadIdx.x;
    int n = gid >> 4;
    int k = gid & 15;
    if (n >= N_NODES) return;

    int base = off[n];
    int deg = cnt[n];
    float acc = 0.f;
    int j = 0;
    for (; j + 3 < deg; j += 4) {
        int s0 = csr[base + j + 0];
        int s1 = csr[base + j + 1];
        int s2 = csr[base + j + 2];
        int s3 = csr[base + j + 3];
        acc += p1[s0 * HID + k];
        acc += p1[s1 * HID + k];
        acc += p1[s2 * HID + k];
        acc += p1[s3 * HID + k];
    }
    for (; j < deg; ++j) acc += p1[csr[base + j] * HID + k];
    acc += p1[n * HID + k];                      // self-loop

    float di = dinv[n];
    float h = fmaxf(di * acc + b1[k], 0.f);
    p2[n * HID + k] = di * h;
}

// ---------------- gather layer 2 (+W2/b2/log_softmax fused) ----------------
__global__ __launch_bounds__(256) void k_gather2(const int* __restrict__ csr,
                                                 const int* __restrict__ off,
                                                 const int* __restrict__ cnt,
                                                 const float* __restrict__ p2,
                                                 const float* __restrict__ dinv,
                                                 const float* __restrict__ W2,
                                                 const float* __restrict__ b2,
                                                 float* __restrict__ out) {
    int gid = blockIdx.x * 256 + threadIdx.x;
    int n = gid >> 4;
    int k = gid & 15;
    if (n >= N_NODES) return;

    int base = off[n];
    int deg = cnt[n];
    float acc = 0.f;
    int j = 0;
    for (; j + 3 < deg; j += 4) {
        int s0 = csr[base + j + 0];
        int s1 = csr[base + j + 1];
        int s2 = csr[base + j + 2];
        int s3 = csr[base + j + 3];
        acc += p2[s0 * HID + k];
        acc += p2[s1 * HID + k];
        acc += p2[s2 * HID + k];
        acc += p2[s3 * HID + k];
    }
    for (; j < deg; ++j) acc += p2[csr[base + j] * HID + k];
    acc += p2[n * HID + k];                      // self-loop

    float v = dinv[n] * acc;
    float t0 = v * W2[k * OUTC + 0];
    float t1 = v * W2[k * OUTC + 1];
    // reduce across the 16-lane group
#pragma unroll
    for (int m = 1; m < HID; m <<= 1) {
        t0 += __shfl_xor(t0, m);
        t1 += __shfl_xor(t1, m);
    }
    float v0 = t0 + b2[0];
    float v1 = t1 + b2[1];
    float mx = fmaxf(v0, v1);
    float lse = mx + logf(expf(v0 - mx) + expf(v1 - mx));
    if (k < OUTC) out[n * OUTC + k] = (k == 0 ? v0 : v1) - lse;
}

extern "C" void kernel_launch(void* const* d_in, const int* in_sizes, int n_in,
                              void* d_out, int out_size, void* d_ws, size_t ws_size,
                              hipStream_t stream) {
    const float* x  = (const float*)d_in[0];
    const int*   ei = (const int*)d_in[1];
    const float* W1 = (const float*)d_in[2];
    const float* b1 = (const float*)d_in[3];
    const float* W2 = (const float*)d_in[4];
    const float* b2 = (const float*)d_in[5];
    float* out = (float*)d_out;

    const int* src = ei;             // edge_index[0]
    const int* dst = ei + N_EDGES;   // edge_index[1]

    // workspace layout (bytes):
    char* ws = (char*)d_ws;
    int*   cnt  = (int*)ws;                               // 400 KB
    int*   off  = cnt + N_NODES;                          // 400 KB
    float* dinv = (float*)(off + N_NODES);                // 400 KB
    int*   bsum = (int*)(dinv + N_NODES);                 // 196 B
    int*   boff = bsum + SCAN_NB;                         // 196 B
    int*   rank = (int*)(((uintptr_t)(boff + SCAN_NB) + 255) & ~(uintptr_t)255); // 12.8 MB
    int*   csr  = rank + N_EDGES;                         // 12.8 MB
    float* p2   = (float*)(csr + N_EDGES);                // 6.4 MB
    float* p1   = (float*)rank;   // alias: rank is dead after k_fill

    hipMemsetAsync(cnt, 0, (size_t)N_NODES * sizeof(int), stream);

    k_count_rank<<<(N_EDGES + 255) / 256, 256, 0, stream>>>(dst, cnt, rank);
    k_blocksum<<<SCAN_NB, 256, 0, stream>>>(cnt, bsum);
    k_scanb<<<1, 64, 0, stream>>>(bsum, boff);
    k_offsets<<<SCAN_NB, 256, 0, stream>>>(cnt, boff, off, dinv);
    k_fill<<<(N_EDGES + 255) / 256, 256, 0, stream>>>(src, dst, rank, off, csr);
    // rank dead from here; p1 aliases it
    k_gemm1<<<(N_NODES * 16 + 255) / 256, 256, 0, stream>>>(x, W1, dinv, p1);
    k_gather1<<<(N_NODES * 16 + 255) / 256, 256, 0, stream>>>(csr, off, cnt, p1, dinv, b1, p2);
    k_gather2<<<(N_NODES * 16 + 255) / 256, 256, 0, stream>>>(csr, off, cnt, p2, dinv, W2, b2, out);
}

// Round 4
// 226.741 us; speedup vs baseline: 3.0717x; 1.3569x over previous
//
#include <hip/hip_runtime.h>

#define N_NODES 100000
#define N_EDGES 3200000
#define IN_DIM  128
#define HID     16
#define OUTC    2

// CSR-build geometry
#define P_PARTS  8
#define PART_SZ  12500                  // nodes per partition (50 KB LDS)
#define B_CHUNKS 64
#define CHUNK    (N_EDGES / B_CHUNKS)   // 50000 edges per chunk

// scan geometry
#define SCAN_ELEMS 2048                 // per block (256 thr x 8)
#define SCAN_NB    49                   // ceil(100000/2048)

// ---------------- phase A: partitioned LDS count ----------------
__global__ __launch_bounds__(256) void k_pcount(const int* __restrict__ dst,
                                                int* __restrict__ partial) {
    __shared__ int h[PART_SZ];
    int p = blockIdx.x % P_PARTS;
    int b = blockIdx.x / P_PARTS;
    int lo = p * PART_SZ;

    for (int i = threadIdx.x; i < PART_SZ; i += 256) h[i] = 0;
    __syncthreads();

    const int4* d4 = (const int4*)(dst + b * CHUNK);
    for (int i = threadIdx.x; i < CHUNK / 4; i += 256) {
        int4 v = d4[i];
        if ((unsigned)(v.x - lo) < PART_SZ) atomicAdd(&h[v.x - lo], 1);
        if ((unsigned)(v.y - lo) < PART_SZ) atomicAdd(&h[v.y - lo], 1);
        if ((unsigned)(v.z - lo) < PART_SZ) atomicAdd(&h[v.z - lo], 1);
        if ((unsigned)(v.w - lo) < PART_SZ) atomicAdd(&h[v.w - lo], 1);
    }
    __syncthreads();

    int* outp = partial + (size_t)b * N_NODES + lo;
    for (int i = threadIdx.x; i < PART_SZ; i += 256) outp[i] = h[i];
}

// ---------------- phase B: per-node exclusive scan over chunks (in place) ----------------
__global__ __launch_bounds__(256) void k_colscan(int* __restrict__ partial,
                                                 int* __restrict__ cnt) {
    int n = blockIdx.x * 256 + threadIdx.x;
    if (n >= N_NODES) return;
    int run = 0;
#pragma unroll 8
    for (int b = 0; b < B_CHUNKS; ++b) {
        int* pp = partial + (size_t)b * N_NODES + n;
        int v = *pp;
        *pp = run;          // rank base for chunk b
        run += v;
    }
    cnt[n] = run;
}

// ---------------- node scan (a): per-block sums ----------------
__global__ __launch_bounds__(256) void k_blocksum(const int* __restrict__ cnt,
                                                  int* __restrict__ bsum) {
    __shared__ int s[256];
    int base = blockIdx.x * SCAN_ELEMS + threadIdx.x * 8;
    int t = 0;
#pragma unroll
    for (int i = 0; i < 8; ++i) {
        int idx = base + i;
        t += (idx < N_NODES) ? cnt[idx] : 0;
    }
    s[threadIdx.x] = t;
    __syncthreads();
    for (int ofs = 128; ofs > 0; ofs >>= 1) {
        if (threadIdx.x < ofs) s[threadIdx.x] += s[threadIdx.x + ofs];
        __syncthreads();
    }
    if (threadIdx.x == 0) bsum[blockIdx.x] = s[0];
}

// ---------------- node scan (b): serial scan of block sums ----------------
__global__ __launch_bounds__(64) void k_scanb(const int* __restrict__ bsum,
                                              int* __restrict__ boff) {
    if (threadIdx.x == 0) {
        int run = 0;
        for (int b = 0; b < SCAN_NB; ++b) { boff[b] = run; run += bsum[b]; }
    }
}

// ---------------- node scan (c): final offsets + dinv ----------------
__global__ __launch_bounds__(256) void k_offsets(const int* __restrict__ cnt,
                                                 const int* __restrict__ boff,
                                                 int* __restrict__ off,
                                                 float* __restrict__ dinv) {
    __shared__ int s[256];
    int base = blockIdx.x * SCAN_ELEMS + threadIdx.x * 8;
    int c[8];
    int tsum = 0;
#pragma unroll
    for (int i = 0; i < 8; ++i) {
        int idx = base + i;
        c[i] = (idx < N_NODES) ? cnt[idx] : 0;
        tsum += c[i];
    }
    s[threadIdx.x] = tsum;
    __syncthreads();
    for (int ofs = 1; ofs < 256; ofs <<= 1) {
        int v = (threadIdx.x >= ofs) ? s[threadIdx.x - ofs] : 0;
        __syncthreads();
        s[threadIdx.x] += v;
        __syncthreads();
    }
    int tbase = boff[blockIdx.x] + s[threadIdx.x] - tsum;  // exclusive prefix
    int run = 0;
#pragma unroll
    for (int i = 0; i < 8; ++i) {
        int idx = base + i;
        if (idx < N_NODES) {
            off[idx] = tbase + run;
            dinv[idx] = rsqrtf(1.0f + (float)c[i]);   // + self-loop
        }
        run += c[i];
    }
}

// ---------------- phase C: LDS rank + CSR fill (atomic-free globally) ----------------
__global__ __launch_bounds__(256) void k_rankfill(const int* __restrict__ src,
                                                  const int* __restrict__ dst,
                                                  const int* __restrict__ partial, // rank bases
                                                  const int* __restrict__ off,
                                                  int* __restrict__ csr) {
    __shared__ int h[PART_SZ];
    int p = blockIdx.x % P_PARTS;
    int b = blockIdx.x / P_PARTS;
    int lo = p * PART_SZ;

    const int* rb = partial + (size_t)b * N_NODES + lo;
    for (int i = threadIdx.x; i < PART_SZ; i += 256) h[i] = rb[i];
    __syncthreads();

    const int4* d4 = (const int4*)(dst + b * CHUNK);
    const int4* s4 = (const int4*)(src + b * CHUNK);
    for (int i = threadIdx.x; i < CHUNK / 4; i += 256) {
        int4 dv = d4[i];
        int4 sv = s4[i];
        if ((unsigned)(dv.x - lo) < PART_SZ) { int r = atomicAdd(&h[dv.x - lo], 1); csr[off[dv.x] + r] = sv.x; }
        if ((unsigned)(dv.y - lo) < PART_SZ) { int r = atomicAdd(&h[dv.y - lo], 1); csr[off[dv.y] + r] = sv.y; }
        if ((unsigned)(dv.z - lo) < PART_SZ) { int r = atomicAdd(&h[dv.z - lo], 1); csr[off[dv.z] + r] = sv.z; }
        if ((unsigned)(dv.w - lo) < PART_SZ) { int r = atomicAdd(&h[dv.w - lo], 1); csr[off[dv.w] + r] = sv.w; }
    }
}

// ---------------- p1 = dinv * (x @ W1) ----------------
__global__ __launch_bounds__(256) void k_gemm1(const float* __restrict__ x,
                                               const float* __restrict__ W1,
                                               const float* __restrict__ dinv,
                                               float* __restrict__ p1) {
    __shared__ float sW[IN_DIM * HID];
    for (int i = threadIdx.x; i < IN_DIM * HID; i += 256) sW[i] = W1[i];
    __syncthreads();

    int gid = blockIdx.x * 256 + threadIdx.x;
    int n = gid >> 4;
    int k = gid & 15;
    if (n >= N_NODES) return;

    const float* xr = x + (size_t)n * IN_DIM;
    float acc = 0.f;
#pragma unroll 8
    for (int j = 0; j < IN_DIM; ++j)
        acc = fmaf(xr[j], sW[j * HID + k], acc);

    p1[n * HID + k] = acc * dinv[n];
}

// ---------------- gather layer 1 (+relu/b1 and W2 fused) ----------------
// p2b[n][c] = sum_k (dinv[n]*relu(dinv[n]*(Σ_{s} p1[s][k] + p1[n][k]) + b1[k])) * W2[k][c]
__global__ __launch_bounds__(256) void k_gather1(const int* __restrict__ csr,
                                                 const int* __restrict__ off,
                                                 const int* __restrict__ cnt,
                                                 const float* __restrict__ p1,
                                                 const float* __restrict__ dinv,
                                                 const float* __restrict__ b1,
                                                 const float* __restrict__ W2,
                                                 float* __restrict__ p2b) {
    int gid = blockIdx.x * 256 + threadIdx.x;
    int n = gid >> 4;
    int k = gid & 15;
    if (n >= N_NODES) return;

    int base = off[n];
    int deg = cnt[n];
    float acc = 0.f;
    int j = 0;
    for (; j + 3 < deg; j += 4) {
        int s0 = csr[base + j + 0];
        int s1 = csr[base + j + 1];
        int s2 = csr[base + j + 2];
        int s3 = csr[base + j + 3];
        acc += p1[s0 * HID + k];
        acc += p1[s1 * HID + k];
        acc += p1[s2 * HID + k];
        acc += p1[s3 * HID + k];
    }
    for (; j < deg; ++j) acc += p1[csr[base + j] * HID + k];
    acc += p1[n * HID + k];                      // self-loop

    float di = dinv[n];
    float hval = fmaxf(fmaf(di, acc, b1[k]), 0.f);
    float hv = di * hval;
    float t0 = hv * W2[k * OUTC + 0];
    float t1 = hv * W2[k * OUTC + 1];
#pragma unroll
    for (int m = 1; m < HID; m <<= 1) {
        t0 += __shfl_xor(t0, m);
        t1 += __shfl_xor(t1, m);
    }
    if (k == 0) *(float2*)(p2b + n * OUTC) = make_float2(t0, t1);
}

// ---------------- gather layer 2 (+b2/log_softmax fused) ----------------
__global__ __launch_bounds__(256) void k_gather2(const int* __restrict__ csr,
                                                 const int* __restrict__ off,
                                                 const int* __restrict__ cnt,
                                                 const float* __restrict__ p2b,
                                                 const float* __restrict__ dinv,
                                                 const float* __restrict__ b2,
                                                 float* __restrict__ out) {
    int gid = blockIdx.x * 256 + threadIdx.x;
    int n = gid >> 4;
    int k = gid & 15;
    if (n >= N_NODES) return;

    int base = off[n];
    int deg = cnt[n];
    float a0 = 0.f, a1 = 0.f;
    for (int j = k; j < deg; j += 16) {          // 16-lane coalesced csr walk
        int s = csr[base + j];
        float2 v = *(const float2*)(p2b + s * OUTC);
        a0 += v.x;
        a1 += v.y;
    }
    if (k == 0) {                                // self-loop once
        float2 v = *(const float2*)(p2b + n * OUTC);
        a0 += v.x;
        a1 += v.y;
    }
#pragma unroll
    for (int m = 1; m < HID; m <<= 1) {
        a0 += __shfl_xor(a0, m);
        a1 += __shfl_xor(a1, m);
    }
    if (k == 0) {
        float di = dinv[n];
        float v0 = fmaf(di, a0, b2[0]);
        float v1 = fmaf(di, a1, b2[1]);
        float mx = fmaxf(v0, v1);
        float lse = mx + logf(expf(v0 - mx) + expf(v1 - mx));
        *(float2*)(out + n * OUTC) = make_float2(v0 - lse, v1 - lse);
    }
}

extern "C" void kernel_launch(void* const* d_in, const int* in_sizes, int n_in,
                              void* d_out, int out_size, void* d_ws, size_t ws_size,
                              hipStream_t stream) {
    const float* x  = (const float*)d_in[0];
    const int*   ei = (const int*)d_in[1];
    const float* W1 = (const float*)d_in[2];
    const float* b1 = (const float*)d_in[3];
    const float* W2 = (const float*)d_in[4];
    const float* b2 = (const float*)d_in[5];
    float* out = (float*)d_out;

    const int* src = ei;             // edge_index[0]
    const int* dst = ei + N_EDGES;   // edge_index[1]

    // workspace layout
    char* ws = (char*)d_ws;
    int*   partial = (int*)ws;                            // 64 x 100000 ints = 25.6 MB
    int*   cnt  = partial + (size_t)B_CHUNKS * N_NODES;   // 400 KB
    int*   off  = cnt + N_NODES;                          // 400 KB
    float* dinv = (float*)(off + N_NODES);                // 400 KB
    int*   bsum = (int*)(dinv + N_NODES);
    int*   boff = bsum + SCAN_NB;
    int*   csr  = (int*)(((uintptr_t)(boff + SCAN_NB) + 255) & ~(uintptr_t)255); // 12.8 MB
    float* p2b  = (float*)(csr + N_EDGES);                // 800 KB
    float* p1   = (float*)partial;   // alias: partial dead after k_rankfill

    k_pcount  <<<P_PARTS * B_CHUNKS, 256, 0, stream>>>(dst, partial);
    k_colscan <<<(N_NODES + 255) / 256, 256, 0, stream>>>(partial, cnt);
    k_blocksum<<<SCAN_NB, 256, 0, stream>>>(cnt, bsum);
    k_scanb   <<<1, 64, 0, stream>>>(bsum, boff);
    k_offsets <<<SCAN_NB, 256, 0, stream>>>(cnt, boff, off, dinv);
    k_rankfill<<<P_PARTS * B_CHUNKS, 256, 0, stream>>>(src, dst, partial, off, csr);
    // partial dead; p1 aliases it
    k_gemm1   <<<(N_NODES * 16 + 255) / 256, 256, 0, stream>>>(x, W1, dinv, p1);
    k_gather1 <<<(N_NODES * 16 + 255) / 256, 256, 0, stream>>>(csr, off, cnt, p1, dinv, b1, W2, p2b);
    k_gather2 <<<(N_NODES * 16 + 255) / 256, 256, 0, stream>>>(csr, off, cnt, p2b, dinv, b2, out);
}